// Round 1
// baseline (146.737 us; speedup 1.0000x reference)
//
#include <hip/hip_runtime.h>

typedef unsigned int u32;
typedef unsigned short u16;
typedef __attribute__((ext_vector_type(4))) float fx4;
typedef __attribute__((ext_vector_type(8))) short s16x8;

#define DD 128
#define KK 1024

__device__ __forceinline__ u16 f2bf(float f) {
  u32 u = __float_as_uint(f);
  return (u16)((u + 0x7FFFu + ((u >> 16) & 1u)) >> 16);
}

__device__ __forceinline__ u32 umin32(u32 a, u32 b) { return a < b ? a : b; }

typedef __attribute__((address_space(1))) const unsigned char ga_byte;
typedef __attribute__((address_space(3))) unsigned char ls_byte;

__device__ __forceinline__ void gl_lds16(const void* g, void* l) {
  __builtin_amdgcn_global_load_lds((ga_byte*)g, (ls_byte*)l, 16, 0, 0);
}

// ---------------- prep: cb fp32 -> bf16, e2b = 0.5 + 0.5*sum(cb^2), zero loss acc
extern "C" __global__ __launch_bounds__(256) void rvq_prep(
    const float* __restrict__ cbf, u16* __restrict__ cbw,
    float* __restrict__ e2b, float* __restrict__ acc) {
  if (blockIdx.x == 0 && threadIdx.x == 0) acc[0] = 0.f;
  const int row = blockIdx.x * 4 + (threadIdx.x >> 6);  // 0..4095 (M*K)
  const int lane = threadIdx.x & 63;
  const float2 v = *(const float2*)(cbf + (size_t)row * DD + lane * 2);
  const u32 pk = (u32)f2bf(v.x) | ((u32)f2bf(v.y) << 16);
  *(u32*)(cbw + (size_t)row * DD + lane * 2) = pk;
  float s = v.x * v.x + v.y * v.y;
#pragma unroll
  for (int m = 32; m >= 1; m >>= 1) s += __shfl_xor(s, m, 64);
  if (lane == 0) e2b[row] = 0.5f + 0.5f * s;
}

// ---------------- main: 512 blocks x 256 thr; block = 64 rows; wave = 32 rows x 512-col half
extern "C" __global__ __launch_bounds__(256, 2) void rvq_main(
    const float* __restrict__ x, const float* __restrict__ cbf,
    const u16* __restrict__ cbw, const float* __restrict__ e2b,
    float* __restrict__ yout, float* __restrict__ lossacc) {
  // [buf][half][col(64)][k(128)] bf16, ku-swizzled: element (col, ku*8+j) stored at sk = ku ^ (col&7)
  __shared__ u16 cbt[2][2][64][128];  // 65536 B
  u32* lmin = (u32*)&cbt[1][0][0][0]; // aliases buf1 head; only used in epilogues (buf1 idle there)

  const int tid = threadIdx.x;
  const int w = tid >> 6;
  const int lane = tid & 63;
  const int c = lane & 15;   // col-in-tile for B/C, row m for A
  const int q = lane >> 4;   // quad
  const int h = w & 1;       // column half (0: cols 0-511, 1: 512-1023)
  const int pair = w >> 1;   // row pair
  const int rowbase = blockIdx.x * 64 + pair * 32;

  // staging lane constants: wave w stages units [w*512, w*512+512)
  u32 goffs[8];
#pragma unroll
  for (int j = 0; j < 8; ++j) {
    const int cc = h * 32 + j * 4 + q;        // local col in chunk
    const int ku = c ^ (cc & 7);              // fetch ku so that stored sk == c
    goffs[j] = (u32)((pair * 512 + cc) * 128 + ku * 8);  // elements, within a level-chunk block
  }
  // B-frag read byte offsets (within a buf): h*16384 + c*256 + sk*16, sk=(4s+q)^(c&7)
  u32 vaddrB[4];
#pragma unroll
  for (int s = 0; s < 4; ++s)
    vaddrB[s] = (u32)(h * 16384 + c * 256 + (((4 * s + q) ^ (c & 7)) * 16));

  float R[2][4][8];   // negated residual, fp32: R[t2][s][j] = -res[row=t2*16+c][d=s*32+q*8+j]
  s16x8 afr[2][4];    // bf16 copy (A fragments)

#pragma unroll
  for (int t2 = 0; t2 < 2; ++t2) {
    const float* xr = x + (size_t)(rowbase + t2 * 16 + c) * DD + q * 8;
#pragma unroll
    for (int s = 0; s < 4; ++s) {
      fx4 a = *(const fx4*)(xr + s * 32);
      fx4 b = *(const fx4*)(xr + s * 32 + 4);
#pragma unroll
      for (int j = 0; j < 4; ++j) { R[t2][s][j] = -a[j]; R[t2][s][4 + j] = -b[j]; }
      s16x8 af;
#pragma unroll
      for (int j = 0; j < 8; ++j) af[j] = (short)f2bf(R[t2][s][j]);
      afr[t2][s] = af;
    }
  }

  u32 run[2][4];
#pragma unroll
  for (int t2 = 0; t2 < 2; ++t2)
#pragma unroll
    for (int r = 0; r < 4; ++r) run[t2][r] = 0xFFFFFFFFu;

  float lsum = 0.f;

  { // prologue: stage level0 chunk0 -> buf0
    char* lb = (char*)&cbt[0][0][0][0] + w * 8192 + lane * 16;
#pragma unroll
    for (int j = 0; j < 8; ++j) gl_lds16(cbw + goffs[j], lb + j * 1024);
  }

  for (int it = 0; it < 32; ++it) {
    const int lvl = it >> 3, chunk = it & 7, buf = it & 1;
    __syncthreads();  // drains in-flight gl_lds for this chunk
    if (it + 1 < 32) {  // prefetch next chunk into the other buffer
      const int nl = (it + 1) >> 3, nc = (it + 1) & 7, nb = (it + 1) & 1;
      const u16* gb = cbw + (size_t)nl * (KK * DD) + nc * 8192;
      char* lb = (char*)&cbt[0][0][0][0] + nb * 32768 + w * 8192 + lane * 16;
#pragma unroll
      for (int j = 0; j < 8; ++j) gl_lds16(gb + goffs[j], lb + j * 1024);
    }
    float e2v[4];
    {
      const float* e2p = e2b + lvl * KK + h * 512 + chunk * 64 + c;
#pragma unroll
      for (int t = 0; t < 4; ++t) e2v[t] = e2p[t * 16];
    }
    const char* lbB = (const char*)&cbt[0][0][0][0] + buf * 32768;
    const u32 colb = (u32)(chunk * 64 + c);
#pragma unroll
    for (int t = 0; t < 4; ++t) {
      fx4 acc0 = {e2v[t], e2v[t], e2v[t], e2v[t]};  // acc = 0.5 + e2/2 - r.c  (positive, in (0.375,0.75))
      fx4 acc1 = acc0;
#pragma unroll
      for (int s = 0; s < 4; ++s) {
        const s16x8 bf = *(const s16x8*)(lbB + vaddrB[s] + t * 4096);
        acc0 = __builtin_amdgcn_mfma_f32_16x16x32_bf16(afr[0][s], bf, acc0, 0, 0, 0);
        acc1 = __builtin_amdgcn_mfma_f32_16x16x32_bf16(afr[1][s], bf, acc1, 0, 0, 0);
      }
#pragma unroll
      for (int r = 0; r < 4; ++r) {
        const u32 p0 = ((__float_as_uint(acc0[r]) - 0x3EC00000u) << 9) | (colb + t * 16);
        const u32 p1 = ((__float_as_uint(acc1[r]) - 0x3EC00000u) << 9) | (colb + t * 16);
        run[0][r] = umin32(run[0][r], p0);
        run[1][r] = umin32(run[1][r], p1);
      }
    }

    if (chunk == 7) {  // ---- level epilogue
      __syncthreads();  // everyone done reading buf1; lmin (aliasing buf1) now safe
      // reduce over the 16 cols held by this quad's lanes
#pragma unroll
      for (int m = 1; m < 16; m <<= 1)
#pragma unroll
        for (int t2 = 0; t2 < 2; ++t2)
#pragma unroll
          for (int r = 0; r < 4; ++r)
            run[t2][r] = umin32(run[t2][r], (u32)__shfl_xor((int)run[t2][r], m, 64));
      if (c == 0) {
        u32* lp = lmin + (pair * 2 + h) * 32;
#pragma unroll
        for (int t2 = 0; t2 < 2; ++t2)
#pragma unroll
          for (int r = 0; r < 4; ++r) lp[t2 * 16 + q * 4 + r] = run[t2][r];
      }
      __syncthreads();
#pragma unroll
      for (int t2 = 0; t2 < 2; ++t2) {
        const u32 p0 = lmin[(pair * 2 + 0) * 32 + t2 * 16 + c];
        const u32 p1 = lmin[(pair * 2 + 1) * 32 + t2 * 16 + c];
        const int col = (p1 < p0) ? (int)(p1 & 511u) + 512 : (int)(p0 & 511u);
        const float* qp = cbf + ((size_t)lvl * KK + col) * DD + q * 8;
#pragma unroll
        for (int s = 0; s < 4; ++s) {
          const fx4 qa = *(const fx4*)(qp + s * 32);
          const fx4 qb = *(const fx4*)(qp + s * 32 + 4);
#pragma unroll
          for (int j = 0; j < 4; ++j) { R[t2][s][j] += qa[j]; R[t2][s][4 + j] += qb[j]; }
          s16x8 af;
#pragma unroll
          for (int j = 0; j < 8; ++j) {
            lsum = fmaf(R[t2][s][j], R[t2][s][j], lsum);  // (q - res_old)^2, exact fp32
            af[j] = (short)f2bf(R[t2][s][j]);
          }
          afr[t2][s] = af;
        }
      }
#pragma unroll
      for (int t2 = 0; t2 < 2; ++t2)
#pragma unroll
        for (int r = 0; r < 4; ++r) run[t2][r] = 0xFFFFFFFFu;
    }
  }

  if (h == 0) {  // halves hold identical R; write once
#pragma unroll
    for (int t2 = 0; t2 < 2; ++t2) {
      const size_t base = (size_t)(rowbase + t2 * 16 + c) * DD + q * 8;
#pragma unroll
      for (int s = 0; s < 4; ++s) {
        const fx4 xa = *(const fx4*)(x + base + s * 32);
        const fx4 xb = *(const fx4*)(x + base + s * 32 + 4);
        fx4 ya, yb;
#pragma unroll
        for (int j = 0; j < 4; ++j) { ya[j] = xa[j] + R[t2][s][j]; yb[j] = xb[j] + R[t2][s][4 + j]; }
        *(fx4*)(yout + base + s * 32) = ya;
        *(fx4*)(yout + base + s * 32 + 4) = yb;
      }
    }
#pragma unroll
    for (int m = 32; m >= 1; m >>= 1) lsum += __shfl_xor(lsum, m, 64);
    if (lane == 0) atomicAdd(lossacc, lsum);
  }
}

extern "C" __global__ void rvq_final(const float* __restrict__ acc, float* __restrict__ out) {
  out[0] = acc[0] * (1.25f / 4194304.f);  // 1.25/(N*D)
}

extern "C" void kernel_launch(void* const* d_in, const int* in_sizes, int n_in,
                              void* d_out, int out_size, void* d_ws, size_t ws_size,
                              hipStream_t stream) {
  const float* x = (const float*)d_in[0];     // [32768,128]
  const float* cbf = (const float*)d_in[1];   // [4,1024,128]
  float* y = (float*)d_out;
  float* lossout = y + (out_size - 1);
  float* acc = (float*)d_ws;
  u16* cbw = (u16*)((char*)d_ws + 256);                    // 1 MiB bf16 codebook
  float* e2b = (float*)((char*)d_ws + 256 + 1048576);      // 16 KiB biased half-norms

  rvq_prep<<<1024, 256, 0, stream>>>(cbf, cbw, e2b, acc);
  rvq_main<<<512, 256, 0, stream>>>(x, cbf, cbw, e2b, y, acc);
  rvq_final<<<1, 1, 0, stream>>>(acc, lossout);
}